// Round 1
// baseline (5832.940 us; speedup 1.0000x reference)
//
#include <hip/hip_runtime.h>
#include <stdint.h>

// CustomRNN: B=128, S=1024, I=256, H=512, O=64, all fp32 in/out.
// Single persistent kernel, 64 WGs = 8 domains (16 batch rows) x 8 members (64 h-cols).
// W slices live in LDS for the whole run; h handoff via global bf16 double-buffer +
// per-(domain,step) release/acquire counters in d_ws.

#define B_  128
#define S_  1024
#define I_  256
#define H_  512
#define O_  64
#define GB_ 8      // domains (batch slices of 16)
#define GN_ 8      // members per domain (h-col slices of 64)
#define BW_ 16     // batch rows per domain
#define NW_ 64     // h cols per member
#define TPB 256    // 4 waves

typedef short bf16x8 __attribute__((ext_vector_type(8)));
typedef float f32x4  __attribute__((ext_vector_type(4)));

// ---- LDS layout (units: shorts for bf16 regions) ----
#define WHH_OFF 0                         // [64][512] bf16 W_hh^T slice (col-major, swizzled)
#define WIH_OFF (NW_*H_)                  // [64][256] bf16 W_ih^T slice
#define WHO_OFF (WIH_OFF + NW_*I_)        // [16][512] bf16 W_ho^T slice (8 real + 8 zero cols)
#define HST_OFF (WHO_OFF + 16*H_)         // [16][512] bf16 h_{t-1} stage
#define XST_OFF (HST_OFF + BW_*H_)        // [16][256] bf16 X_t stage
#define SH_SHORTS (XST_OFF + BW_*I_)      // 69632 shorts = 139264 B
#define YP_OFFB  (SH_SHORTS*2)            // [4][16][16] f32 y partials (4096 B)
#define BHH_OFFB (YP_OFFB + 4*16*16*4)    // [64] f32
#define BHO_OFFB (BHH_OFFB + NW_*4)       // [8] f32
#define LDS_BYTES (BHO_OFFB + 64)         // 143680 B < 160 KiB

// ws layout: cnt[8][1024] u32 at 0 (memset to 0 each launch); hbuf[2][128][512] bf16 at 64 KiB
#define CNT_BYTES (GB_*S_*4)
#define HBUF_OFFB 65536
#define WS_NEEDED (HBUF_OFFB + 2*B_*H_*2)

__device__ __forceinline__ short f2bf(float f) {   // RNE float->bf16 (no NaN inputs here)
  unsigned u = __builtin_bit_cast(unsigned, f);
  u += 0x7FFFu + ((u >> 16) & 1u);
  return (short)(u >> 16);
}
__device__ __forceinline__ float fast_tanh(float x) {
  // tanh(x) = 1 - 2/(exp(2x)+1); v_exp + v_rcp, abs err < ~1e-6, saturates correctly
  float e = __expf(2.0f * x);
  return 1.0f - 2.0f * __builtin_amdgcn_rcpf(e + 1.0f);
}
// XOR-swizzle (G4): row-major LDS tiles with 512/1024 B row stride are 16-way bank
// conflicts on ds_read_b128; flip short-idx bits 3..5 by (row&7).
__device__ __forceinline__ int swz(int r, int k) { return k ^ ((r & 7) << 3); }
__device__ __forceinline__ int whh_ix(int c, int k) { return WHH_OFF + (c << 9) + swz(c, k); }
__device__ __forceinline__ int wih_ix(int c, int k) { return WIH_OFF + (c << 8) + swz(c, k); }
__device__ __forceinline__ int who_ix(int c, int k) { return WHO_OFF + (c << 9) + swz(c, k); }
__device__ __forceinline__ int hst_ix(int r, int k) { return HST_OFF + (r << 9) + swz(r, k); }
__device__ __forceinline__ int xst_ix(int r, int k) { return XST_OFF + (r << 8) + swz(r, k); }

__global__ __launch_bounds__(TPB, 1) void rnn_persistent(
    const float* __restrict__ Xg,   // [B,S,I]
    const float* __restrict__ Whh,  // [H,H]
    const float* __restrict__ Wih,  // [I,H]
    const float* __restrict__ bhh,  // [H]
    const float* __restrict__ Who,  // [H,O]
    const float* __restrict__ bho,  // [O]
    float* __restrict__ Out,        // [B,S,O]
    unsigned* __restrict__ cnt,     // [GB_][S_]
    unsigned short* __restrict__ hbuf) // [2][B_][H_] bf16
{
  extern __shared__ char smem[];
  short* sh    = (short*)smem;
  float* ypart = (float*)(smem + YP_OFFB);
  float* bhh_s = (float*)(smem + BHH_OFFB);
  float* bho_s = (float*)(smem + BHO_OFFB);

  const int tid = threadIdx.x;
  const int bid = blockIdx.x;
  const int d = bid & 7;    // domain -> XCD d under round-robin dispatch
  const int m = bid >> 3;   // member (h-col slice)
  const int w = tid >> 6;   // wave 0..3 (owns n-cols [w*16, w*16+16) of this member's 64)
  const int l = tid & 63;
  const int col16 = l & 15; // MFMA A-row / B-col / D-col lane coordinate
  const int kq = l >> 4;    // k-quarter: lane holds k = kq*8 .. kq*8+7 of each 32-K step

  // ---------------- stage weights into LDS (once) ----------------
  for (int idx = tid; idx < NW_*H_; idx += TPB) {   // W_hh[:, m*64+c] -> [c][k]
    int c = idx & 63, k = idx >> 6;
    sh[whh_ix(c, k)] = f2bf(Whh[k * H_ + m * NW_ + c]);
  }
  for (int idx = tid; idx < NW_*I_; idx += TPB) {
    int c = idx & 63, k = idx >> 6;
    sh[wih_ix(c, k)] = f2bf(Wih[k * H_ + m * NW_ + c]);
  }
  for (int idx = tid; idx < 16*H_; idx += TPB) {    // W_ho cols m*8..+8, padded to 16 with 0
    int c = idx & 15, k = idx >> 4;
    float v = (c < 8) ? Who[k * O_ + m * 8 + c] : 0.0f;
    sh[who_ix(c, k)] = f2bf(v);
  }
  if (tid < NW_) bhh_s[tid] = bhh[m * NW_ + tid];
  if (tid < 8)   bho_s[tid] = bho[m * 8 + tid];

  // X prefetch: thread (r=tid>>4, ch=tid&15) owns 16 floats of the [16,256] tile
  const int xr = tid >> 4, xch = tid & 15;
  const float* xbase = Xg + (size_t)(d * BW_ + xr) * S_ * I_ + xch * 16;
  float4 P0, P1, P2, P3;
  {
    const float4* p = (const float4*)(xbase);      // t = 0
    P0 = p[0]; P1 = p[1]; P2 = p[2]; P3 = p[3];
  }
  __syncthreads();

  unsigned* mycnt = cnt + d * S_;
  int guard = 0;  // global poll budget: breaks an accidental deadlock instead of wedging

  for (int t = 0; t <= S_; ++t) {
    if (t > 0) {
      // wait for all 8 members' h_{t-1}; acquire gives L1/L2-stale invalidation
      while (__hip_atomic_load(&mycnt[t - 1], __ATOMIC_ACQUIRE, __HIP_MEMORY_SCOPE_AGENT) < GN_) {
        if (++guard > (1 << 24)) break;
      }
      // stage h_{t-1} [16,512] bf16 -> LDS (swizzled)
      const unsigned short* hsrc =
          hbuf + (size_t)((t - 1) & 1) * B_ * H_ + (size_t)(d * BW_ + xr) * H_ + xch * 32;
      bf16x8 h0 = *(const bf16x8*)(hsrc + 0);
      bf16x8 h1 = *(const bf16x8*)(hsrc + 8);
      bf16x8 h2 = *(const bf16x8*)(hsrc + 16);
      bf16x8 h3 = *(const bf16x8*)(hsrc + 24);
      *(bf16x8*)&sh[hst_ix(xr, xch * 32 + 0)]  = h0;
      *(bf16x8*)&sh[hst_ix(xr, xch * 32 + 8)]  = h1;
      *(bf16x8*)&sh[hst_ix(xr, xch * 32 + 16)] = h2;
      *(bf16x8*)&sh[hst_ix(xr, xch * 32 + 24)] = h3;
    }
    if (t < S_) {
      // stage X(t) from prefetch regs (cvt fp32->bf16), then issue prefetch of X(t+1)
      bf16x8 lo, hi;
      lo[0] = f2bf(P0.x); lo[1] = f2bf(P0.y); lo[2] = f2bf(P0.z); lo[3] = f2bf(P0.w);
      lo[4] = f2bf(P1.x); lo[5] = f2bf(P1.y); lo[6] = f2bf(P1.z); lo[7] = f2bf(P1.w);
      hi[0] = f2bf(P2.x); hi[1] = f2bf(P2.y); hi[2] = f2bf(P2.z); hi[3] = f2bf(P2.w);
      hi[4] = f2bf(P3.x); hi[5] = f2bf(P3.y); hi[6] = f2bf(P3.z); hi[7] = f2bf(P3.w);
      *(bf16x8*)&sh[xst_ix(xr, xch * 16 + 0)] = lo;
      *(bf16x8*)&sh[xst_ix(xr, xch * 16 + 8)] = hi;
      if (t + 1 < S_) {
        const float4* p = (const float4*)(xbase + (size_t)(t + 1) * I_);
        P0 = p[0]; P1 = p[1]; P2 = p[2]; P3 = p[3];
      }
    }
    __syncthreads();

    if (t < S_) {
      // z = h_{t-1} @ Whh_slice + X_t @ Wih_slice + b_hh  -> per wave one 16x16 tile
      float bv = bhh_s[w * 16 + col16];
      f32x4 acc = {bv, bv, bv, bv};
      if (t > 0) {
#pragma unroll
        for (int ks = 0; ks < 16; ++ks) {
          bf16x8 a = *(const bf16x8*)&sh[hst_ix(col16, kq * 8 + ks * 32)];
          bf16x8 b = *(const bf16x8*)&sh[whh_ix(w * 16 + col16, kq * 8 + ks * 32)];
          acc = __builtin_amdgcn_mfma_f32_16x16x32_bf16(a, b, acc, 0, 0, 0);
        }
      }
#pragma unroll
      for (int ks = 0; ks < 8; ++ks) {
        bf16x8 a = *(const bf16x8*)&sh[xst_ix(col16, kq * 8 + ks * 32)];
        bf16x8 b = *(const bf16x8*)&sh[wih_ix(w * 16 + col16, kq * 8 + ks * 32)];
        acc = __builtin_amdgcn_mfma_f32_16x16x32_bf16(a, b, acc, 0, 0, 0);
      }
      // h_t = tanh(z); store bf16 to global double-buffer (D: col=l&15, row=kq*4+j)
      const size_t hb = (size_t)(t & 1) * B_ * H_;
      const int gcol = m * NW_ + w * 16 + col16;
#pragma unroll
      for (int j = 0; j < 4; ++j) {
        int row = d * BW_ + kq * 4 + j;
        hbuf[hb + (size_t)row * H_ + gcol] = (unsigned short)f2bf(fast_tanh(acc[j]));
      }
      __syncthreads();  // all waves' stores drained (vmcnt0 before s_barrier)
      if (tid == 0)
        __hip_atomic_fetch_add(&mycnt[t], 1u, __ATOMIC_RELEASE, __HIP_MEMORY_SCOPE_AGENT);
    }

    if (t > 0) {
      // y_{t-1} = h_{t-1} @ W_ho + b_ho, k-split over 4 waves, LDS reduce
      f32x4 ay = {0.0f, 0.0f, 0.0f, 0.0f};
#pragma unroll
      for (int q = 0; q < 4; ++q) {
        int ks = w * 4 + q;
        bf16x8 a = *(const bf16x8*)&sh[hst_ix(col16, kq * 8 + ks * 32)];
        bf16x8 b = *(const bf16x8*)&sh[who_ix(col16, kq * 8 + ks * 32)];
        ay = __builtin_amdgcn_mfma_f32_16x16x32_bf16(a, b, ay, 0, 0, 0);
      }
#pragma unroll
      for (int j = 0; j < 4; ++j)
        ypart[w * 256 + (kq * 4 + j) * 16 + col16] = ay[j];
      __syncthreads();
      if (tid < 128) {
        int i = tid >> 3, c = tid & 7;
        float s = ypart[0 * 256 + i * 16 + c] + ypart[1 * 256 + i * 16 + c] +
                  ypart[2 * 256 + i * 16 + c] + ypart[3 * 256 + i * 16 + c] + bho_s[c];
        Out[((size_t)(d * BW_ + i) * S_ + (t - 1)) * O_ + m * 8 + c] = s;
      }
    }
    __syncthreads();  // protect h_st/X_st/ypart against next iteration's staging
  }
}

extern "C" void kernel_launch(void* const* d_in, const int* in_sizes, int n_in,
                              void* d_out, int out_size, void* d_ws, size_t ws_size,
                              hipStream_t stream) {
  const float* Xg  = (const float*)d_in[0];
  const float* Whh = (const float*)d_in[1];
  const float* Wih = (const float*)d_in[2];
  const float* bhh = (const float*)d_in[3];
  const float* Who = (const float*)d_in[4];
  const float* bho = (const float*)d_in[5];
  float* Out = (float*)d_out;
  if (ws_size < (size_t)WS_NEEDED) return;  // should not happen (needs 320 KiB)

  unsigned* cnt = (unsigned*)d_ws;
  unsigned short* hbuf = (unsigned short*)((char*)d_ws + HBUF_OFFB);

  hipFuncSetAttribute((const void*)rnn_persistent,
                      hipFuncAttributeMaxDynamicSharedMemorySize, LDS_BYTES);
  hipMemsetAsync(d_ws, 0, CNT_BYTES, stream);  // zero the step counters each call

  hipLaunchKernelGGL(rnn_persistent, dim3(GB_ * GN_), dim3(TPB), LDS_BYTES, stream,
                     Xg, Whh, Wih, bhh, Who, bho, Out, cnt, hbuf);
}

// Round 2
// 3319.611 us; speedup vs baseline: 1.7571x; 1.7571x over previous
//
#include <hip/hip_runtime.h>
#include <stdint.h>

// CustomRNN: B=128, S=1024, I=256, H=512, O=64, fp32 in/out.
// 64 persistent WGs = 8 domains (16 batch rows) x 8 members (64 h-cols).
// Round 2: relaxed MALL-bypass atomics for the h handoff (no acquire/release
// cache ops), per-wave release/poll, fragment-order W in LDS (conflict-free
// B reads), h-independent work moved off the critical chain.

#define B_  128
#define S_  1024
#define I_  256
#define H_  512
#define O_  64
#define GB_ 8      // domains
#define GN_ 8      // members per domain
#define BW_ 16     // batch rows per domain
#define NW_ 64     // h cols per member
#define TPB 256    // 4 waves
#define REL_TARGET 32u   // 8 members x 4 waves release per step

typedef short bf16x8 __attribute__((ext_vector_type(8)));
typedef float f32x4  __attribute__((ext_vector_type(4)));

// ---- LDS layout (units: shorts) ----
#define WHH_OFF 0          // frag-order [w:4][ks:16][lane:64] x 8 shorts = 32768
#define WIH_OFF 32768      // frag-order [w:4][ks:8][lane:64] x 8       = 16384
#define WHO_OFF 49152      // frag-order [ks:16][lane:64] x 8           = 8192
#define HST_OFF 57344      // [16][512] row-major swizzled              = 8192
#define XST_OFF 65536      // [16][256] row-major swizzled              = 4096
#define SH_SHORTS 69632
#define YP_OFFB  (SH_SHORTS*2)           // [4][16][16] f32 = 4096 B
#define BHH_OFFB (YP_OFFB + 4096)        // [64] f32
#define BHO_OFFB (BHH_OFFB + 256)        // [8] f32
#define LDS_BYTES (BHO_OFFB + 64)        // 143680 B < 160 KiB

// ws: cnt[8][1024] u32 at 0 (memset each launch); hbuf[2][128][512] bf16 at 64 KiB
#define CNT_BYTES (GB_*S_*4)
#define HBUF_OFFB 65536
#define WS_NEEDED (HBUF_OFFB + 2*B_*H_*2)

__device__ __forceinline__ short f2bf(float f) {   // RNE float->bf16
  unsigned u = __builtin_bit_cast(unsigned, f);
  u += 0x7FFFu + ((u >> 16) & 1u);
  return (short)(u >> 16);
}
__device__ __forceinline__ float fast_tanh(float x) {
  float e = __expf(2.0f * x);
  return 1.0f - 2.0f * __builtin_amdgcn_rcpf(e + 1.0f);
}
// A-side swizzle (h/X row-major tiles): flips short-idx bits 3..5 by row&7.
__device__ __forceinline__ int swz(int r, int k) { return k ^ ((r & 7) << 3); }
__device__ __forceinline__ int hst_ix(int r, int k) { return HST_OFF + (r << 9) + swz(r, k); }
__device__ __forceinline__ int xst_ix(int r, int k) { return XST_OFF + (r << 8) + swz(r, k); }

__global__ __launch_bounds__(TPB, 1) void rnn_persistent(
    const float* __restrict__ Xg,   // [B,S,I]
    const float* __restrict__ Whh,  // [H,H]
    const float* __restrict__ Wih,  // [I,H]
    const float* __restrict__ bhh,  // [H]
    const float* __restrict__ Who,  // [H,O]
    const float* __restrict__ bho,  // [O]
    float* __restrict__ Out,        // [B,S,O]
    unsigned* __restrict__ cnt,     // [GB_][S_]
    unsigned short* __restrict__ hbuf) // [2][B_][H_] bf16
{
  extern __shared__ char smem[];
  short* sh    = (short*)smem;
  float* ypart = (float*)(smem + YP_OFFB);
  float* bhh_s = (float*)(smem + BHH_OFFB);
  float* bho_s = (float*)(smem + BHO_OFFB);

  const int tid = threadIdx.x;
  const int d = blockIdx.x & 7;   // domain -> XCD under round-robin (perf heuristic only)
  const int m = blockIdx.x >> 3;  // member
  const int w = tid >> 6;         // wave 0..3 (owns n-cols w*16..w*16+16)
  const int l = tid & 63;
  const int col16 = l & 15;
  const int kq = l >> 4;

  // ---------------- stage weights into LDS in MFMA fragment order ----------------
  // B-frag for 16x16x32: lane holds B[k=(l>>4)*8+j + ks*32][n=l&15]
  for (int q = tid; q < 4096; q += TPB) {              // Whh
    int lq = q & 63, ks = (q >> 6) & 15, wq = q >> 10;
    int n = m * NW_ + wq * 16 + (lq & 15);
    int kb = ks * 32 + (lq >> 4) * 8;
    bf16x8 v;
#pragma unroll
    for (int j = 0; j < 8; ++j) v[j] = f2bf(Whh[(size_t)(kb + j) * H_ + n]);
    *(bf16x8*)&sh[WHH_OFF + q * 8] = v;
  }
  for (int q = tid; q < 2048; q += TPB) {              // Wih
    int lq = q & 63, ks = (q >> 6) & 7, wq = q >> 9;
    int n = m * NW_ + wq * 16 + (lq & 15);
    int kb = ks * 32 + (lq >> 4) * 8;
    bf16x8 v;
#pragma unroll
    for (int j = 0; j < 8; ++j) v[j] = f2bf(Wih[(size_t)(kb + j) * H_ + n]);
    *(bf16x8*)&sh[WIH_OFF + q * 8] = v;
  }
  for (int q = tid; q < 1024; q += TPB) {              // Who (8 real cols + 8 zero pad)
    int lq = q & 63, ks = q >> 6;
    int n = lq & 15;
    int kb = ks * 32 + (lq >> 4) * 8;
    bf16x8 v;
#pragma unroll
    for (int j = 0; j < 8; ++j)
      v[j] = (n < 8) ? f2bf(Who[(size_t)(kb + j) * O_ + m * 8 + n]) : (short)0;
    *(bf16x8*)&sh[WHO_OFF + q * 8] = v;
  }
  if (tid < NW_) bhh_s[tid] = bhh[m * NW_ + tid];
  if (tid < 8)   bho_s[tid] = bho[m * 8 + tid];

  // X prefetch: thread (xr, xch) owns 16 floats of the [16,256] tile
  const int xr = tid >> 4, xch = tid & 15;
  const float* xbase = Xg + (size_t)(d * BW_ + xr) * S_ * I_ + xch * 16;
  float4 P0, P1, P2, P3;
  { const float4* p = (const float4*)xbase; P0 = p[0]; P1 = p[1]; P2 = p[2]; P3 = p[3]; }

  unsigned* mycnt = cnt + d * S_;
  int guard = 0;

  for (int t = 0; t <= S_; ++t) {
    // A: stage X_t from prefetch regs; issue prefetch of X_{t+1}
    if (t < S_) {
      bf16x8 lo, hi;
      lo[0]=f2bf(P0.x); lo[1]=f2bf(P0.y); lo[2]=f2bf(P0.z); lo[3]=f2bf(P0.w);
      lo[4]=f2bf(P1.x); lo[5]=f2bf(P1.y); lo[6]=f2bf(P1.z); lo[7]=f2bf(P1.w);
      hi[0]=f2bf(P2.x); hi[1]=f2bf(P2.y); hi[2]=f2bf(P2.z); hi[3]=f2bf(P2.w);
      hi[4]=f2bf(P3.x); hi[5]=f2bf(P3.y); hi[6]=f2bf(P3.z); hi[7]=f2bf(P3.w);
      *(bf16x8*)&sh[xst_ix(xr, xch * 16 + 0)] = lo;
      *(bf16x8*)&sh[xst_ix(xr, xch * 16 + 8)] = hi;
      if (t + 1 < S_) {
        const float4* p = (const float4*)(xbase + (size_t)(t + 1) * I_);
        P0 = p[0]; P1 = p[1]; P2 = p[2]; P3 = p[3];
      }
    }
    __syncthreads();  // B1: X_t visible; also fences h/ypart reuse from last iter

    // Early poll issue (value consumed after xacc -> load latency hidden)
    unsigned c0 = REL_TARGET;
    if (t > 0) c0 = __hip_atomic_load(&mycnt[t - 1], __ATOMIC_RELAXED, __HIP_MEMORY_SCOPE_AGENT);

    // C: xacc = b_hh + X_t @ Wih (h-independent, 8 MFMAs, 2 chains)
    f32x4 acc0 = {0.f, 0.f, 0.f, 0.f}, acc1 = {0.f, 0.f, 0.f, 0.f};
    if (t < S_) {
      float bv = bhh_s[w * 16 + col16];
      acc0[0] = bv; acc0[1] = bv; acc0[2] = bv; acc0[3] = bv;
#pragma unroll
      for (int ks = 0; ks < 8; ++ks) {
        bf16x8 a = *(const bf16x8*)&sh[xst_ix(col16, kq * 8 + ks * 32)];
        bf16x8 b = *(const bf16x8*)&sh[WIH_OFF + w * 4096 + ks * 512 + l * 8];
        if (ks & 1) acc1 = __builtin_amdgcn_mfma_f32_16x16x32_bf16(a, b, acc1, 0, 0, 0);
        else        acc0 = __builtin_amdgcn_mfma_f32_16x16x32_bf16(a, b, acc0, 0, 0, 0);
      }
    }

    if (t > 0) {
      // per-wave relaxed poll (no per-iteration cache invalidates)
      if (c0 < REL_TARGET) {
        while (__hip_atomic_load(&mycnt[t - 1], __ATOMIC_RELAXED, __HIP_MEMORY_SCOPE_AGENT) < REL_TARGET) {
          if (++guard > (1 << 22)) break;
        }
      }
      asm volatile("" ::: "memory");
      // E: bypass-load h_{t-1} (64 B/thread) and stage to LDS
      const unsigned long long* hsrc = (const unsigned long long*)
          (hbuf + (size_t)((t - 1) & 1) * B_ * H_ + (size_t)(d * BW_ + xr) * H_ + xch * 32);
      unsigned long long v[8];
#pragma unroll
      for (int i = 0; i < 8; ++i)
        v[i] = __hip_atomic_load(hsrc + i, __ATOMIC_RELAXED, __HIP_MEMORY_SCOPE_AGENT);
#pragma unroll
      for (int i = 0; i < 4; ++i) {
        union { unsigned long long u[2]; bf16x8 b; } pk;
        pk.u[0] = v[2 * i]; pk.u[1] = v[2 * i + 1];
        *(bf16x8*)&sh[hst_ix(xr, xch * 32 + 8 * i)] = pk.b;
      }
      __syncthreads();  // F: h_{t-1} staged

      // G: += h_{t-1} @ Whh (16 MFMAs, 2 chains)
      if (t < S_) {
#pragma unroll
        for (int ks = 0; ks < 16; ++ks) {
          bf16x8 a = *(const bf16x8*)&sh[hst_ix(col16, kq * 8 + ks * 32)];
          bf16x8 b = *(const bf16x8*)&sh[WHH_OFF + w * 8192 + ks * 512 + l * 8];
          if (ks & 1) acc1 = __builtin_amdgcn_mfma_f32_16x16x32_bf16(a, b, acc1, 0, 0, 0);
          else        acc0 = __builtin_amdgcn_mfma_f32_16x16x32_bf16(a, b, acc0, 0, 0, 0);
        }
      }
    }

    // H: h_t = tanh(z); relaxed bypass u16 stores (D-frag: col=l&15, row=kq*4+j)
    if (t < S_) {
      f32x4 z = acc0 + acc1;
      unsigned short* hp = hbuf + (size_t)(t & 1) * B_ * H_
                         + (size_t)(d * BW_ + kq * 4) * H_ + m * NW_ + w * 16 + col16;
#pragma unroll
      for (int j = 0; j < 4; ++j) {
        unsigned short hv = (unsigned short)f2bf(fast_tanh(z[j]));
        __hip_atomic_store(hp + (size_t)j * H_, hv, __ATOMIC_RELAXED, __HIP_MEMORY_SCOPE_AGENT);
      }
    }

    // I1: y_{t-1} = h_{t-1} @ Who (LDS-only; overlaps the h-store ack window)
    f32x4 ay = {0.f, 0.f, 0.f, 0.f};
    if (t > 0) {
#pragma unroll
      for (int q = 0; q < 4; ++q) {
        int ks = w * 4 + q;
        bf16x8 a = *(const bf16x8*)&sh[hst_ix(col16, kq * 8 + ks * 32)];
        bf16x8 b = *(const bf16x8*)&sh[WHO_OFF + ks * 512 + l * 8];
        ay = __builtin_amdgcn_mfma_f32_16x16x32_bf16(a, b, ay, 0, 0, 0);
      }
    }

    // H2: per-wave release — own stores MALL-acked, then relaxed FAA
    if (t < S_) {
      asm volatile("s_waitcnt vmcnt(0)" ::: "memory");
      if (l == 0)
        __hip_atomic_fetch_add(&mycnt[t], 1u, __ATOMIC_RELAXED, __HIP_MEMORY_SCOPE_AGENT);
    }

    // I2: y reduce + output store
    if (t > 0) {
#pragma unroll
      for (int j = 0; j < 4; ++j)
        ypart[w * 256 + (kq * 4 + j) * 16 + col16] = ay[j];
      __syncthreads();
      if (tid < 128) {
        int i = tid >> 3, c = tid & 7;
        float s = ypart[i * 16 + c] + ypart[256 + i * 16 + c] +
                  ypart[512 + i * 16 + c] + ypart[768 + i * 16 + c] + bho_s[c];
        Out[((size_t)(d * BW_ + i) * S_ + (t - 1)) * O_ + m * 8 + c] = s;
      }
    }
  }
}

extern "C" void kernel_launch(void* const* d_in, const int* in_sizes, int n_in,
                              void* d_out, int out_size, void* d_ws, size_t ws_size,
                              hipStream_t stream) {
  const float* Xg  = (const float*)d_in[0];
  const float* Whh = (const float*)d_in[1];
  const float* Wih = (const float*)d_in[2];
  const float* bhh = (const float*)d_in[3];
  const float* Who = (const float*)d_in[4];
  const float* bho = (const float*)d_in[5];
  float* Out = (float*)d_out;
  if (ws_size < (size_t)WS_NEEDED) return;

  unsigned* cnt = (unsigned*)d_ws;
  unsigned short* hbuf = (unsigned short*)((char*)d_ws + HBUF_OFFB);

  hipFuncSetAttribute((const void*)rnn_persistent,
                      hipFuncAttributeMaxDynamicSharedMemorySize, LDS_BYTES);
  hipMemsetAsync(d_ws, 0, CNT_BYTES, stream);

  hipLaunchKernelGGL(rnn_persistent, dim3(GB_ * GN_), dim3(TPB), LDS_BYTES, stream,
                     Xg, Whh, Wih, bhh, Who, bho, Out, cnt, hbuf);
}